// Round 3
// baseline (312.861 us; speedup 1.0000x reference)
//
#include <hip/hip_runtime.h>

typedef float  f32x4  __attribute__((ext_vector_type(4)));
typedef float  f32x16 __attribute__((ext_vector_type(16)));
typedef short  s16x8  __attribute__((ext_vector_type(8)));
typedef unsigned u32x2 __attribute__((ext_vector_type(2)));
typedef int    i32x4  __attribute__((ext_vector_type(4)));

#define SEQ 2048
#define DH  128
#define BN  32
#define NTILE 32   // tiles per KV-half (1024/32)

// fp32 -> 2x bf16 packed (RNE via native __bf16; compiler emits v_cvt_pk_bf16_f32)
__device__ __forceinline__ unsigned pk2bf(float a, float b){
  union { __bf16 h[2]; unsigned u; } x;
  x.h[0] = (__bf16)a; x.h[1] = (__bf16)b; return x.u;
}

__device__ __forceinline__ void gl16(const unsigned short* g, void* s){
  __builtin_amdgcn_global_load_lds(
      (const __attribute__((address_space(1))) void*)g,
      (__attribute__((address_space(3))) void*)s, 16, 0, 0);
}

// ---- pre-pass 1: K fp32 -> bf16 (row-major copy) ----
__global__ __launch_bounds__(256) void cvt_k(const float* __restrict__ in,
                                             unsigned short* __restrict__ out){
  size_t id = (size_t)blockIdx.x*256 + threadIdx.x;
  f32x4 v = *(const f32x4*)(in + id*4);
  u32x2 o; o[0] = pk2bf(v[0], v[1]); o[1] = pk2bf(v[2], v[3]);
  *(u32x2*)(out + id*4) = o;
}

// ---- pre-pass 2: V fp32 [bh][kv][d] -> bf16 transposed Vt [bh][d][kv] ----
__global__ __launch_bounds__(256) void cvt_vt(const float* __restrict__ V,
                                              unsigned short* __restrict__ Vt){
  __shared__ float tile[32][33];
  const int bid = blockIdx.x;
  const int bh = bid >> 8, t5 = bid & 255;
  const int kv0 = (t5 >> 2) * 32, d0 = (t5 & 3) * 32;
  const int r = threadIdx.x >> 3, c = (threadIdx.x & 7) * 4;
  f32x4 v = *(const f32x4*)(V + ((size_t)bh*SEQ + kv0 + r)*DH + d0 + c);
  tile[r][c+0]=v[0]; tile[r][c+1]=v[1]; tile[r][c+2]=v[2]; tile[r][c+3]=v[3];
  __syncthreads();
  u32x2 o;
  o[0] = pk2bf(tile[c+0][r], tile[c+1][r]);
  o[1] = pk2bf(tile[c+2][r], tile[c+3][r]);
  *(u32x2*)(Vt + ((size_t)bh*DH + d0 + r)*SEQ + kv0 + c) = o;
}

// ---- main: flash attention fwd, non-causal ----
// 512 thr = 8 waves = 4 q-pairs x 2 KV-halves. Wave owns 32 q rows, 1024 kv.
// T3/T4 sync: raw s_barrier + counted vmcnt(4); issue(t+2) into freed slab.
// Loads stay in flight ACROSS barriers (never drained mid-loop).
__global__ __launch_bounds__(512, 4)
void sdpa_fwd(const float* __restrict__ Qg, const unsigned short* __restrict__ Kbf,
              const unsigned short* __restrict__ Vtb, float* __restrict__ Og)
{
  __shared__ __align__(16) char smem[68608];
  // loop: (half,db) slabs of 16KB: [K 8KB | V 8KB]  (64KB)
  // epilogue (aliased): obuf[4][32][132] f32, mbuf[4][32] @67584, lbuf @68096

  const int tid = threadIdx.x;
  const int w = tid >> 6, l = tid & 63, ln = l & 31, h2 = l >> 5;
  const int half = w >> 2, pair = w & 3;

  const int bid = (int)blockIdx.x;
  const int bh = ((bid & 7) << 2) | ((bid >> 3) & 3);   // XCD-chunked, bijective
  const int qt = bid >> 5;

  const float* Qb = Qg + (size_t)bh*(SEQ*DH);
  const unsigned short* Kb = Kbf + (size_t)bh*(SEQ*DH);
  const unsigned short* Vb = Vtb + (size_t)bh*(SEQ*DH);  // [DH][SEQ]
  float* Ob = Og + (size_t)bh*(SEQ*DH);

  const int qrow = qt*128 + pair*32 + ln;
  const float qsc = 0.1275174156f;   // log2(e)/sqrt(128): exp2-domain softmax

  // Q fragments (B-operand), 8 k-steps of 16
  s16x8 qf[8];
#pragma unroll
  for (int kc = 0; kc < 8; ++kc) {
    const float* p = Qb + (size_t)qrow*DH + kc*16 + h2*8;
    f32x4 a = *(const f32x4*)p, b = *(const f32x4*)(p+4);
    i32x4 t;
    t[0] = (int)pk2bf(a[0]*qsc, a[1]*qsc);
    t[1] = (int)pk2bf(a[2]*qsc, a[3]*qsc);
    t[2] = (int)pk2bf(b[0]*qsc, b[1]*qsc);
    t[3] = (int)pk2bf(b[2]*qsc, b[3]*qsc);
    qf[kc] = __builtin_bit_cast(s16x8, t);
  }

  // per-wave gload assignments: K insts {pair, pair+4}, V insts {pair, pair+4}
  const int i0 = pair, i1 = pair + 4;
  const unsigned short* kg0 = Kb + ((size_t)(half*1024) + (ln ^ ((2*i0+h2)&7)))*DH + 16*i0 + 8*h2;
  const unsigned short* kg1 = Kb + ((size_t)(half*1024) + (ln ^ ((2*i1+h2)&7)))*DH + 16*i1 + 8*h2;
  const unsigned short* vg0 = Vb + (size_t)(32*(i0&3) + (ln ^ ((2*(i0&3)+h2)&7)))*SEQ
                                 + half*1024 + 16*(i0>>2) + 8*h2;
  const unsigned short* vg1 = Vb + (size_t)(32*(i1&3) + (ln ^ ((2*(i1&3)+h2)&7)))*SEQ
                                 + half*1024 + 16*(i1>>2) + 8*h2;

  f32x16 ot[4];
#pragma unroll
  for (int dt = 0; dt < 4; ++dt)
#pragma unroll
    for (int r = 0; r < 16; ++r) ot[dt][r] = 0.f;
  float m_run = -1e30f, l_run = 0.f;   // l_run per-lane partial; pair-reduced at end

  auto issue = [&](int t, int db) {
    char* base = smem + (size_t)(half*2 + db)*16384;
    gl16(kg0 + (size_t)t*(BN*DH), base + i0*1024);
    gl16(kg1 + (size_t)t*(BN*DH), base + i1*1024);
    gl16(vg0 + t*BN, base + 8192 + i0*1024);
    gl16(vg1 + t*BN, base + 8192 + i1*1024);
  };

  issue(0, 0);
  issue(1, 1);          // 8 loads in flight

  int db = 0;
  for (int t = 0; t < NTILE; ++t) {
    // tile t's 4 loads (oldest) must have landed; keep tile t+1's in flight
    if (t < NTILE-1) { asm volatile("s_waitcnt vmcnt(4)" ::: "memory"); }
    else             { asm volatile("s_waitcnt vmcnt(0)" ::: "memory"); }
    __builtin_amdgcn_sched_barrier(0);
    __builtin_amdgcn_s_barrier();       // all waves' tile-t loads landed
    __builtin_amdgcn_sched_barrier(0);

    const char* base = smem + (size_t)(half*2 + db)*16384;

    // ---- QK^T: S^T[kv][q], 8 k-steps ----
    f32x16 sa;
#pragma unroll
    for (int r = 0; r < 16; ++r) sa[r] = 0.f;
    __builtin_amdgcn_s_setprio(1);
#pragma unroll
    for (int kc = 0; kc < 8; ++kc) {
      const int frag = 2*kc + h2;
      s16x8 a = *(const s16x8*)(base + frag*512 + ((ln ^ (frag & 7)) << 4));
      sa = __builtin_amdgcn_mfma_f32_32x32x16_bf16(a, qf[kc], sa, 0, 0, 0);
    }
    __builtin_amdgcn_s_setprio(0);

    // ---- online softmax, exp2 domain, per-row defer-max (THR=8) ----
    float x0 = fmaxf(sa[0], sa[1]),  x1 = fmaxf(sa[2], sa[3]);
    float x2 = fmaxf(sa[4], sa[5]),  x3 = fmaxf(sa[6], sa[7]);
    float x4 = fmaxf(sa[8], sa[9]),  x5 = fmaxf(sa[10], sa[11]);
    float x6 = fmaxf(sa[12], sa[13]), x7 = fmaxf(sa[14], sa[15]);
    float tmax = fmaxf(fmaxf(fmaxf(x0,x1), fmaxf(x2,x3)),
                       fmaxf(fmaxf(x4,x5), fmaxf(x6,x7)));
    tmax = fmaxf(tmax, __shfl_xor(tmax, 32));
    if (!__all(tmax <= m_run + 8.f)) {
      const float mnew = fmaxf(m_run, tmax);
      const float al = __builtin_amdgcn_exp2f(m_run - mnew);
      l_run *= al;
#pragma unroll
      for (int dt = 0; dt < 4; ++dt)
#pragma unroll
        for (int r = 0; r < 16; ++r) ot[dt][r] *= al;
      m_run = mnew;
    }
    float psum = 0.f;
#pragma unroll
    for (int r = 0; r < 16; ++r) {
      sa[r] = __builtin_amdgcn_exp2f(sa[r] - m_run);
      psum += sa[r];
    }
    l_run += psum;   // per-lane partial; cross-half reduce deferred to epilogue

    // ---- P -> bf16 B-frags in-register (cvt_pk + permlane32_swap) ----
    i32x4 pw[2];
#pragma unroll
    for (int ks = 0; ks < 2; ++ks) {
      unsigned a0 = pk2bf(sa[8*ks+0], sa[8*ks+1]);
      unsigned a1 = pk2bf(sa[8*ks+2], sa[8*ks+3]);
      unsigned b0 = pk2bf(sa[8*ks+4], sa[8*ks+5]);
      unsigned b1 = pk2bf(sa[8*ks+6], sa[8*ks+7]);
      u32x2 s0 = __builtin_amdgcn_permlane32_swap(a0, b0, false, false);
      u32x2 s1 = __builtin_amdgcn_permlane32_swap(a1, b1, false, false);
      i32x4 b; b[0] = (int)s0[0]; b[1] = (int)s1[0]; b[2] = (int)s0[1]; b[3] = (int)s1[1];
      pw[ks] = b;
    }

    // ---- PV: O^T += V^T-frag x P^T-frag ----
    __builtin_amdgcn_s_setprio(1);
#pragma unroll
    for (int ks = 0; ks < 2; ++ks) {
      s16x8 pb = __builtin_bit_cast(s16x8, pw[ks]);
#pragma unroll
      for (int dt = 0; dt < 4; ++dt) {
        const int frag = 2*(ks*4 + dt) + h2;
        s16x8 va = *(const s16x8*)(base + 8192 + frag*512 + ((ln ^ (frag & 7)) << 4));
        ot[dt] = __builtin_amdgcn_mfma_f32_32x32x16_bf16(va, pb, ot[dt], 0, 0, 0);
      }
    }
    __builtin_amdgcn_s_setprio(0);

    // all LDS reads of slab db are consumed above (MFMA deps force lgkm waits)
    __builtin_amdgcn_sched_barrier(0);
    __builtin_amdgcn_s_barrier();       // everyone done reading slab db
    __builtin_amdgcn_sched_barrier(0);
    if (t + 2 < NTILE) issue(t + 2, db);   // overwrite freed slab; spans barriers
    db ^= 1;
  }

  // ---- merge KV-halves (upper waves publish; lower waves combine+store) ----
  l_run += __shfl_xor(l_run, 32);      // deferred cross-half l reduction
  float* obuf = (float*)smem;          // [4][32][132]
  float* mbuf = (float*)(smem + 67584);
  float* lbuf = (float*)(smem + 68096);
  if (half == 1) {
    mbuf[pair*32 + ln] = m_run;
    lbuf[pair*32 + ln] = l_run;
    float* orow = obuf + (size_t)(pair*32 + ln)*132;
#pragma unroll
    for (int dt = 0; dt < 4; ++dt)
#pragma unroll
      for (int rq = 0; rq < 4; ++rq) {
        f32x4 v;
        v[0] = ot[dt][rq*4+0]; v[1] = ot[dt][rq*4+1];
        v[2] = ot[dt][rq*4+2]; v[3] = ot[dt][rq*4+3];
        *(f32x4*)(orow + dt*32 + rq*8 + h2*4) = v;
      }
  }
  __syncthreads();
  if (half == 0) {
    const float m1 = mbuf[pair*32 + ln], l1 = lbuf[pair*32 + ln];
    const float ms = fmaxf(m_run, m1);
    const float a0 = __builtin_amdgcn_exp2f(m_run - ms);
    const float a1 = __builtin_amdgcn_exp2f(m1 - ms);
    const float inv = 1.f / (l_run*a0 + l1*a1);
    const float s0 = a0*inv, s1 = a1*inv;
    const float* orow = obuf + (size_t)(pair*32 + ln)*132;
#pragma unroll
    for (int dt = 0; dt < 4; ++dt)
#pragma unroll
      for (int rq = 0; rq < 4; ++rq) {
        f32x4 o1 = *(const f32x4*)(orow + dt*32 + rq*8 + h2*4);
        f32x4 o;
#pragma unroll
        for (int k = 0; k < 4; ++k) o[k] = ot[dt][rq*4+k]*s0 + o1[k]*s1;
        *(f32x4*)(Ob + (size_t)qrow*DH + dt*32 + rq*8 + h2*4) = o;
      }
  }
}

extern "C" void kernel_launch(void* const* d_in, const int* in_sizes, int n_in,
                              void* d_out, int out_size, void* d_ws, size_t ws_size,
                              hipStream_t stream)
{
  (void)in_sizes; (void)n_in; (void)out_size; (void)ws_size;
  const float* Q = (const float*)d_in[0];
  const float* K = (const float*)d_in[1];
  const float* V = (const float*)d_in[2];
  float* O = (float*)d_out;
  unsigned short* Kbf = (unsigned short*)d_ws;          // 16,777,216 B
  unsigned short* Vt  = Kbf + (size_t)32*SEQ*DH;        // 16,777,216 B

  hipLaunchKernelGGL(cvt_k,  dim3(8192), dim3(256), 0, stream, K, Kbf);
  hipLaunchKernelGGL(cvt_vt, dim3(8192), dim3(256), 0, stream, V, Vt);
  hipLaunchKernelGGL(sdpa_fwd, dim3(512), dim3(512), 0, stream, Q, Kbf, Vt, O);
}

// Round 5
// 203.196 us; speedup vs baseline: 1.5397x; 1.5397x over previous
//
#include <hip/hip_runtime.h>

typedef float  f32x4  __attribute__((ext_vector_type(4)));
typedef float  f32x16 __attribute__((ext_vector_type(16)));
typedef short  s16x8  __attribute__((ext_vector_type(8)));
typedef unsigned u32x2 __attribute__((ext_vector_type(2)));
typedef int    i32x4  __attribute__((ext_vector_type(4)));
typedef unsigned short ushort_t;

#define SEQ 2048
#define DH  128
#define BN  64
#define NTILE (SEQ/BN)   // 32 KV tiles of 64

// fp32 -> 2x bf16 packed (RNE; compiler emits v_cvt_pk_bf16_f32)
__device__ __forceinline__ unsigned pk2bf(float a, float b){
  union { __bf16 h[2]; unsigned u; } x;
  x.h[0] = (__bf16)a; x.h[1] = (__bf16)b; return x.u;
}

__device__ __forceinline__ void gl16(const ushort_t* g, void* s){
  __builtin_amdgcn_global_load_lds(
      (const __attribute__((address_space(1))) void*)g,
      (__attribute__((address_space(3))) void*)s, 16, 0, 0);
}

// ---- pre-pass: build fragment-linear bf16 K / V(transposed) tiles ----
// Kf/Vf: [bh][t(32)][frag(16)][lane(64) x 16B].
// K frag fk=mm*8+kc, lane l: K[kv0+32mm+(l&31)][16kc+8*(l>>5)+j], j=0..7
// V frag fv=ks*4+dt, lane l: V[kv0+16ks+8*(l>>5)+j][32dt+(l&31)]  (transpose)
__global__ __launch_bounds__(256)
void build_frags(const float* __restrict__ K, const float* __restrict__ V,
                 ushort_t* __restrict__ Kf, ushort_t* __restrict__ Vf)
{
  __shared__ float vls[64][132];
  const int bid = blockIdx.x;            // 32 bh x 32 t
  const int bh = bid >> 5, t = bid & 31;
  const int kv0 = t * BN;
  const float* Kb = K + ((size_t)bh*SEQ + kv0)*DH;
  const float* Vb = V + ((size_t)bh*SEQ + kv0)*DH;
  const size_t obase = ((size_t)(bh*32 + t)*16) * 512;   // shorts

  // stage V tile (64x128 fp32) into LDS, coalesced
  {
    const int r = threadIdx.x & 63, cg = threadIdx.x >> 6;
#pragma unroll
    for (int i = 0; i < 8; ++i) {
      f32x4 v = *(const f32x4*)(Vb + (size_t)r*DH + cg*32 + i*4);
      *(f32x4*)(&vls[r][cg*32 + i*4]) = v;
    }
  }
  // K fragments straight from global (no transpose needed)
#pragma unroll
  for (int ii = 0; ii < 4; ++ii) {
    const int it = threadIdx.x*4 + ii;     // 0..1023
    const int fk = it >> 6, l = it & 63;
    const int mm = fk >> 3, kc = fk & 7;
    const float* src = Kb + (size_t)(32*mm + (l&31))*DH + kc*16 + (l>>5)*8;
    f32x4 a = *(const f32x4*)src, b = *(const f32x4*)(src+4);
    i32x4 o;
    o[0] = (int)pk2bf(a[0], a[1]); o[1] = (int)pk2bf(a[2], a[3]);
    o[2] = (int)pk2bf(b[0], b[1]); o[3] = (int)pk2bf(b[2], b[3]);
    *(i32x4*)(Kf + obase + (size_t)fk*512 + l*8) = o;
  }
  __syncthreads();
  // V fragments from LDS (transposed gather)
#pragma unroll
  for (int ii = 0; ii < 4; ++ii) {
    const int it = threadIdx.x*4 + ii;
    const int fv = it >> 6, l = it & 63;
    const int ks = fv >> 2, dt = fv & 3;
    const int row0 = 16*ks + 8*(l>>5), col = 32*dt + (l&31);
    i32x4 o;
    o[0] = (int)pk2bf(vls[row0+0][col], vls[row0+1][col]);
    o[1] = (int)pk2bf(vls[row0+2][col], vls[row0+3][col]);
    o[2] = (int)pk2bf(vls[row0+4][col], vls[row0+5][col]);
    o[3] = (int)pk2bf(vls[row0+6][col], vls[row0+7][col]);
    *(i32x4*)(Vf + obase + (size_t)fv*512 + l*8) = o;
  }
}

// ---- main: flash attention fwd, non-causal ----
// 256 blocks (1/CU), 512 thr = 8 waves x 32 q-rows (BM=256). KV tiles of 64.
// Swapped QK^T (A=K,B=Q): softmax per-lane. PV: O^T = V^T x P^T; P in-register
// via cvt_pk+permlane32_swap. K/V via global_load_lds from fragment-linear ws:
// contiguous 1KB per instr, linear LDS, stride-1 ds_read_b128 (bank floor).
// Double-buffered, depth-2 prefetch, counted vmcnt, raw barriers, NO setprio.
__global__ __launch_bounds__(512, 2)
void sdpa_fwd(const float* __restrict__ Qg, const ushort_t* __restrict__ Kf,
              const ushort_t* __restrict__ Vf, float* __restrict__ Og)
{
  __shared__ __align__(16) char smem[65536];  // 2 x [K 16KB | V 16KB]

  const int tid = threadIdx.x;
  const int w = tid >> 6, l = tid & 63, ln = l & 31, h2 = l >> 5;

  const int bid = (int)blockIdx.x;
  // XCD-chunked (256%8==0): XCD x gets bh in [4x,4x+4) -> KV stays L2-local
  const int wg = (bid & 7)*32 + (bid >> 3);
  const int bh = wg >> 3, qt = wg & 7;

  const float* Qb = Qg + (size_t)bh*(SEQ*DH);
  const ushort_t* Kfb = Kf + (size_t)bh*(32*16*512);
  const ushort_t* Vfb = Vf + (size_t)bh*(32*16*512);
  float* Ob = Og + (size_t)bh*(SEQ*DH);

  const int qrow = qt*256 + w*32 + ln;
  const float qsc = 0.1275174156f;   // log2(e)/sqrt(128): exp2-domain softmax

  // Q fragments (B-operand), 8 k-steps of 16
  s16x8 qf[8];
#pragma unroll
  for (int kc = 0; kc < 8; ++kc) {
    const float* p = Qb + (size_t)qrow*DH + kc*16 + h2*8;
    f32x4 a = *(const f32x4*)p, b = *(const f32x4*)(p+4);
    i32x4 t;
    t[0] = (int)pk2bf(a[0]*qsc, a[1]*qsc);
    t[1] = (int)pk2bf(a[2]*qsc, a[3]*qsc);
    t[2] = (int)pk2bf(b[0]*qsc, b[1]*qsc);
    t[3] = (int)pk2bf(b[2]*qsc, b[3]*qsc);
    qf[kc] = __builtin_bit_cast(s16x8, t);
  }

  // per-wave gload srcs: K frags {w, w+8}, V frags {w, w+8}; 8192 shorts/tile
  const ushort_t* kg0 = Kfb + (size_t)w*512 + l*8;
  const ushort_t* kg1 = kg0 + 8*512;
  const ushort_t* vg0 = Vfb + (size_t)w*512 + l*8;
  const ushort_t* vg1 = vg0 + 8*512;

  f32x16 ot[4];
#pragma unroll
  for (int dt = 0; dt < 4; ++dt)
#pragma unroll
    for (int r = 0; r < 16; ++r) ot[dt][r] = 0.f;
  float m_run = -1e30f, l_run = 0.f;

  auto issue = [&](int t, int db) {
    char* slab = smem + db*32768;
    gl16(kg0 + (size_t)t*8192, slab + w*1024);
    gl16(kg1 + (size_t)t*8192, slab + (w+8)*1024);
    gl16(vg0 + (size_t)t*8192, slab + 16384 + w*1024);
    gl16(vg1 + (size_t)t*8192, slab + 16384 + (w+8)*1024);
  };

  issue(0, 0);
  issue(1, 1);            // 8 loads in flight

  int db = 0;
  for (int t = 0; t < NTILE; ++t) {
    if (t < NTILE-1) { asm volatile("s_waitcnt vmcnt(4)" ::: "memory"); }
    else             { asm volatile("s_waitcnt vmcnt(0)" ::: "memory"); }
    __builtin_amdgcn_sched_barrier(0);
    __builtin_amdgcn_s_barrier();       // tile t's 32 frags landed, all waves
    __builtin_amdgcn_sched_barrier(0);

    const char* slab = smem + db*32768;

    // ---- QK^T: S^T[kv][q], 2 kv-blocks x 8 k-steps ----
    f32x16 sa[2];
#pragma unroll
    for (int mm = 0; mm < 2; ++mm) {
#pragma unroll
      for (int r = 0; r < 16; ++r) sa[mm][r] = 0.f;
#pragma unroll
      for (int kc = 0; kc < 8; ++kc) {
        s16x8 a = *(const s16x8*)(slab + (mm*8 + kc)*1024 + l*16);
        sa[mm] = __builtin_amdgcn_mfma_f32_32x32x16_bf16(a, qf[kc], sa[mm], 0, 0, 0);
      }
    }

    // ---- online softmax (exp2 domain, defer-max THR=8) ----
    float tmax = fmaxf(sa[0][0], sa[0][1]);
#pragma unroll
    for (int mm = 0; mm < 2; ++mm)
#pragma unroll
      for (int r = (mm==0?2:0); r < 16; ++r) tmax = fmaxf(tmax, sa[mm][r]);
    tmax = fmaxf(tmax, __shfl_xor(tmax, 32));
    if (!__all(tmax <= m_run + 8.f)) {
      const float mnew = fmaxf(m_run, tmax);
      const float al = __builtin_amdgcn_exp2f(m_run - mnew);
      l_run *= al;
#pragma unroll
      for (int dt = 0; dt < 4; ++dt)
#pragma unroll
        for (int r = 0; r < 16; ++r) ot[dt][r] *= al;
      m_run = mnew;
    }
    float psum = 0.f;
#pragma unroll
    for (int mm = 0; mm < 2; ++mm)
#pragma unroll
      for (int r = 0; r < 16; ++r) {
        sa[mm][r] = __builtin_amdgcn_exp2f(sa[mm][r] - m_run);
        psum += sa[mm][r];
      }
    l_run += psum;   // own-half partial; cross-h2 reduce deferred to epilogue

    // ---- P -> bf16 B-frags in-register (cvt_pk + permlane32_swap) ----
    i32x4 pw[4];
#pragma unroll
    for (int ks = 0; ks < 4; ++ks) {
      const f32x16& s = sa[ks >> 1];
      const int o = 8*(ks & 1);
      unsigned a0 = pk2bf(s[o+0], s[o+1]);
      unsigned a1 = pk2bf(s[o+2], s[o+3]);
      unsigned b0 = pk2bf(s[o+4], s[o+5]);
      unsigned b1 = pk2bf(s[o+6], s[o+7]);
      u32x2 s0 = __builtin_amdgcn_permlane32_swap(a0, b0, false, false);
      u32x2 s1 = __builtin_amdgcn_permlane32_swap(a1, b1, false, false);
      i32x4 b; b[0] = (int)s0[0]; b[1] = (int)s1[0]; b[2] = (int)s0[1]; b[3] = (int)s1[1];
      pw[ks] = b;
    }

    // ---- PV: O^T += V^T-frag x P^T-frag ----
#pragma unroll
    for (int ks = 0; ks < 4; ++ks) {
      s16x8 pb = __builtin_bit_cast(s16x8, pw[ks]);
#pragma unroll
      for (int dt = 0; dt < 4; ++dt) {
        s16x8 va = *(const s16x8*)(slab + 16384 + (ks*4 + dt)*1024 + l*16);
        ot[dt] = __builtin_amdgcn_mfma_f32_32x32x16_bf16(va, pb, ot[dt], 0, 0, 0);
      }
    }

    __builtin_amdgcn_sched_barrier(0);
    __builtin_amdgcn_s_barrier();       // all waves done reading slab db
    __builtin_amdgcn_sched_barrier(0);
    if (t + 2 < NTILE) issue(t + 2, db);   // refill freed slab; spans barriers
    db ^= 1;
  }

  // ---- epilogue: cross-h2 l reduce, normalize, direct f32x4 stores ----
  l_run += __shfl_xor(l_run, 32);
  const float inv = 1.0f / l_run;
#pragma unroll
  for (int dt = 0; dt < 4; ++dt)
#pragma unroll
    for (int rq = 0; rq < 4; ++rq) {
      f32x4 o;
      o[0] = ot[dt][rq*4+0]*inv; o[1] = ot[dt][rq*4+1]*inv;
      o[2] = ot[dt][rq*4+2]*inv; o[3] = ot[dt][rq*4+3]*inv;
      *(f32x4*)(Ob + (size_t)qrow*DH + dt*32 + rq*8 + h2*4) = o;
    }
}

extern "C" void kernel_launch(void* const* d_in, const int* in_sizes, int n_in,
                              void* d_out, int out_size, void* d_ws, size_t ws_size,
                              hipStream_t stream)
{
  (void)in_sizes; (void)n_in; (void)out_size; (void)ws_size;
  const float* Q = (const float*)d_in[0];
  const float* K = (const float*)d_in[1];
  const float* V = (const float*)d_in[2];
  float* O = (float*)d_out;
  ushort_t* Kf = (ushort_t*)d_ws;                       // 16 MB
  ushort_t* Vf = Kf + (size_t)32*32*16*512;             // 16 MB

  hipLaunchKernelGGL(build_frags, dim3(1024), dim3(256), 0, stream, K, V, Kf, Vf);
  hipLaunchKernelGGL(sdpa_fwd,    dim3(256),  dim3(512), 0, stream, Q, Kf, Vf, O);
}

// Round 7
// 202.106 us; speedup vs baseline: 1.5480x; 1.0054x over previous
//
#include <hip/hip_runtime.h>

typedef float  f32x4  __attribute__((ext_vector_type(4)));
typedef float  f32x16 __attribute__((ext_vector_type(16)));
typedef short  s16x8  __attribute__((ext_vector_type(8)));
typedef unsigned u32x2 __attribute__((ext_vector_type(2)));
typedef int    i32x4  __attribute__((ext_vector_type(4)));
typedef unsigned short ushort_t;

#define SEQ 2048
#define DH  128
#define BN  64
#define NTILE (SEQ/BN)   // 32 KV tiles of 64

// fp32 -> 2x bf16 packed (RNE; compiler emits v_cvt_pk_bf16_f32)
__device__ __forceinline__ unsigned pk2bf(float a, float b){
  union { __bf16 h[2]; unsigned u; } x;
  x.h[0] = (__bf16)a; x.h[1] = (__bf16)b; return x.u;
}

__device__ __forceinline__ void gl16(const ushort_t* g, void* s){
  __builtin_amdgcn_global_load_lds(
      (const __attribute__((address_space(1))) void*)g,
      (__attribute__((address_space(3))) void*)s, 16, 0, 0);
}

// ---- pre-pass: build fragment-linear bf16 K / V(transposed) tiles ----
// Kf/Vf: [bh][t(32)][frag(16)][lane(64) x 16B]  (same layout as R5).
// K frag f=mm*8+kc, lane l: K[kv0+32mm+(l&31)][16kc+8*(l>>5)+j], j=0..7
// V frag f=ks*4+dt, lane l: V[kv0+16ks+8*(l>>5)+j][32dt+(l&31)]  (transpose)
// All global reads/writes coalesced; LDS padded to stride 133 (5*row mod 32
// -> 32 distinct banks for the row-gather reads).
__global__ __launch_bounds__(256)
void build_frags(const float* __restrict__ K, const float* __restrict__ V,
                 ushort_t* __restrict__ Kf, ushort_t* __restrict__ Vf)
{
  __shared__ float kls[64][133];
  __shared__ float vls[64][133];
  const int bid = blockIdx.x;            // 32 bh x 32 t
  const int bh = bid >> 5, t = bid & 31;
  const float* Kb = K + ((size_t)bh*SEQ + t*BN)*DH;
  const float* Vb = V + ((size_t)bh*SEQ + t*BN)*DH;
  const size_t obase = (size_t)(bh*32 + t) * 8192;   // shorts

  const int tid = threadIdx.x;
  // coalesced stage: 8 iters x 256 thr x f32x4 (4KB/instr, zero gaps)
#pragma unroll
  for (int i = 0; i < 8; ++i) {
    const int slot = i*256 + tid;        // f32x4 slot 0..2047
    const int row = slot >> 5, col = (slot & 31) * 4;
    f32x4 k4 = *(const f32x4*)(Kb + (size_t)row*DH + col);
    f32x4 v4 = *(const f32x4*)(Vb + (size_t)row*DH + col);
    *(f32x4*)(&kls[row][col]) = k4;
    *(f32x4*)(&vls[row][col]) = v4;
  }
  __syncthreads();

  const int wv = tid >> 6, l = tid & 63;
  const int r31 = l & 31, hh = l >> 5;
  // each wave emits 4 K-frags + 4 V-frags; each frag write = contiguous 1KB
#pragma unroll
  for (int i = 0; i < 4; ++i) {
    const int f = wv*4 + i;              // 0..15
    const int mm = f >> 3, kc = f & 7;
    const float* src = &kls[32*mm + r31][16*kc + 8*hh];
    i32x4 o;
    o[0] = (int)pk2bf(src[0], src[1]); o[1] = (int)pk2bf(src[2], src[3]);
    o[2] = (int)pk2bf(src[4], src[5]); o[3] = (int)pk2bf(src[6], src[7]);
    *(i32x4*)(Kf + obase + (size_t)f*512 + l*8) = o;
  }
#pragma unroll
  for (int i = 0; i < 4; ++i) {
    const int f = wv*4 + i;              // 0..15, = ks*4+dt
    const int ks = f >> 2, dt = f & 3;
    const int col = 32*dt + r31, r0 = 16*ks + 8*hh;
    i32x4 o;
    o[0] = (int)pk2bf(vls[r0+0][col], vls[r0+1][col]);
    o[1] = (int)pk2bf(vls[r0+2][col], vls[r0+3][col]);
    o[2] = (int)pk2bf(vls[r0+4][col], vls[r0+5][col]);
    o[3] = (int)pk2bf(vls[r0+6][col], vls[r0+7][col]);
    *(i32x4*)(Vf + obase + (size_t)f*512 + l*8) = o;
  }
}

// ---- main: flash attention fwd, non-causal (R5 structure, proven 94us) ----
// 256 blocks (1/CU), 512 thr = 8 waves x 32 q-rows (BM=256). KV tiles of 64.
// Swapped QK^T (A=K,B=Q): softmax per-lane. PV: O^T = V^T x P^T; P in-register
// via cvt_pk+permlane32_swap. K/V via global_load_lds from fragment-linear ws.
// Double-buffered, depth-2 prefetch, counted vmcnt, raw barriers, NO setprio.
__global__ __launch_bounds__(512, 2)
void sdpa_fwd(const float* __restrict__ Qg, const ushort_t* __restrict__ Kf,
              const ushort_t* __restrict__ Vf, float* __restrict__ Og)
{
  __shared__ __align__(16) char smem[65536];  // 2 x [K 16KB | V 16KB]

  const int tid = threadIdx.x;
  const int w = tid >> 6, l = tid & 63, ln = l & 31, h2 = l >> 5;

  const int bid = (int)blockIdx.x;
  // XCD-chunked (256%8==0): XCD x gets bh in [4x,4x+4) -> KV stays L2-local
  const int wg = (bid & 7)*32 + (bid >> 3);
  const int bh = wg >> 3, qt = wg & 7;

  const float* Qb = Qg + (size_t)bh*(SEQ*DH);
  const ushort_t* Kfb = Kf + (size_t)bh*(32*16*512);
  const ushort_t* Vfb = Vf + (size_t)bh*(32*16*512);
  float* Ob = Og + (size_t)bh*(SEQ*DH);

  const int qrow = qt*256 + w*32 + ln;
  const float qsc = 0.1275174156f;   // log2(e)/sqrt(128): exp2-domain softmax

  // Q fragments (B-operand), 8 k-steps of 16
  s16x8 qf[8];
#pragma unroll
  for (int kc = 0; kc < 8; ++kc) {
    const float* p = Qb + (size_t)qrow*DH + kc*16 + h2*8;
    f32x4 a = *(const f32x4*)p, b = *(const f32x4*)(p+4);
    i32x4 t;
    t[0] = (int)pk2bf(a[0]*qsc, a[1]*qsc);
    t[1] = (int)pk2bf(a[2]*qsc, a[3]*qsc);
    t[2] = (int)pk2bf(b[0]*qsc, b[1]*qsc);
    t[3] = (int)pk2bf(b[2]*qsc, b[3]*qsc);
    qf[kc] = __builtin_bit_cast(s16x8, t);
  }

  // per-wave gload srcs: K frags {w, w+8}, V frags {w, w+8}; 8192 shorts/tile
  const ushort_t* kg0 = Kfb + (size_t)w*512 + l*8;
  const ushort_t* kg1 = kg0 + 8*512;
  const ushort_t* vg0 = Vfb + (size_t)w*512 + l*8;
  const ushort_t* vg1 = vg0 + 8*512;

  f32x16 ot[4];
#pragma unroll
  for (int dt = 0; dt < 4; ++dt)
#pragma unroll
    for (int r = 0; r < 16; ++r) ot[dt][r] = 0.f;
  float m_run = -1e30f, l_run = 0.f;

  auto issue = [&](int t, int db) {
    char* slab = smem + db*32768;
    gl16(kg0 + (size_t)t*8192, slab + w*1024);
    gl16(kg1 + (size_t)t*8192, slab + (w+8)*1024);
    gl16(vg0 + (size_t)t*8192, slab + 16384 + w*1024);
    gl16(vg1 + (size_t)t*8192, slab + 16384 + (w+8)*1024);
  };

  issue(0, 0);
  issue(1, 1);            // 8 loads in flight

  int db = 0;
  for (int t = 0; t < NTILE; ++t) {
    if (t < NTILE-1) { asm volatile("s_waitcnt vmcnt(4)" ::: "memory"); }
    else             { asm volatile("s_waitcnt vmcnt(0)" ::: "memory"); }
    __builtin_amdgcn_sched_barrier(0);
    __builtin_amdgcn_s_barrier();       // tile t's 32 frags landed, all waves
    __builtin_amdgcn_sched_barrier(0);

    const char* slab = smem + db*32768;

    // ---- QK^T: S^T[kv][q], 2 kv-blocks x 8 k-steps ----
    f32x16 sa[2];
#pragma unroll
    for (int mm = 0; mm < 2; ++mm) {
#pragma unroll
      for (int r = 0; r < 16; ++r) sa[mm][r] = 0.f;
#pragma unroll
      for (int kc = 0; kc < 8; ++kc) {
        s16x8 a = *(const s16x8*)(slab + (mm*8 + kc)*1024 + l*16);
        sa[mm] = __builtin_amdgcn_mfma_f32_32x32x16_bf16(a, qf[kc], sa[mm], 0, 0, 0);
      }
    }

    // ---- online softmax (exp2 domain, defer-max THR=8) ----
    float tmax = fmaxf(sa[0][0], sa[0][1]);
#pragma unroll
    for (int mm = 0; mm < 2; ++mm)
#pragma unroll
      for (int r = (mm==0?2:0); r < 16; ++r) tmax = fmaxf(tmax, sa[mm][r]);
    tmax = fmaxf(tmax, __shfl_xor(tmax, 32));
    if (!__all(tmax <= m_run + 8.f)) {
      const float mnew = fmaxf(m_run, tmax);
      const float al = __builtin_amdgcn_exp2f(m_run - mnew);
      l_run *= al;
#pragma unroll
      for (int dt = 0; dt < 4; ++dt)
#pragma unroll
        for (int r = 0; r < 16; ++r) ot[dt][r] *= al;
      m_run = mnew;
    }
    f32x4 psv; psv[0]=0.f; psv[1]=0.f; psv[2]=0.f; psv[3]=0.f;  // tree psum
#pragma unroll
    for (int mm = 0; mm < 2; ++mm)
#pragma unroll
      for (int r = 0; r < 16; ++r) {
        sa[mm][r] = __builtin_amdgcn_exp2f(sa[mm][r] - m_run);
        psv[r & 3] += sa[mm][r];
      }
    l_run += (psv[0] + psv[1]) + (psv[2] + psv[3]);

    // ---- P -> bf16 B-frags in-register (cvt_pk + permlane32_swap) ----
    i32x4 pw[4];
#pragma unroll
    for (int ks = 0; ks < 4; ++ks) {
      const f32x16& s = sa[ks >> 1];
      const int o = 8*(ks & 1);
      unsigned a0 = pk2bf(s[o+0], s[o+1]);
      unsigned a1 = pk2bf(s[o+2], s[o+3]);
      unsigned b0 = pk2bf(s[o+4], s[o+5]);
      unsigned b1 = pk2bf(s[o+6], s[o+7]);
      u32x2 s0 = __builtin_amdgcn_permlane32_swap(a0, b0, false, false);
      u32x2 s1 = __builtin_amdgcn_permlane32_swap(a1, b1, false, false);
      i32x4 b; b[0] = (int)s0[0]; b[1] = (int)s1[0]; b[2] = (int)s0[1]; b[3] = (int)s1[1];
      pw[ks] = b;
    }

    // ---- PV: O^T += V^T-frag x P^T-frag ----
#pragma unroll
    for (int ks = 0; ks < 4; ++ks) {
      s16x8 pb = __builtin_bit_cast(s16x8, pw[ks]);
#pragma unroll
      for (int dt = 0; dt < 4; ++dt) {
        s16x8 va = *(const s16x8*)(slab + 16384 + (ks*4 + dt)*1024 + l*16);
        ot[dt] = __builtin_amdgcn_mfma_f32_32x32x16_bf16(va, pb, ot[dt], 0, 0, 0);
      }
    }

    __builtin_amdgcn_sched_barrier(0);
    __builtin_amdgcn_s_barrier();       // all waves done reading slab db
    __builtin_amdgcn_sched_barrier(0);
    if (t + 2 < NTILE) issue(t + 2, db);   // refill freed slab; spans barriers
    db ^= 1;
  }

  // ---- epilogue: cross-h2 l reduce, normalize, direct f32x4 stores ----
  l_run += __shfl_xor(l_run, 32);
  const float inv = 1.0f / l_run;
#pragma unroll
  for (int dt = 0; dt < 4; ++dt)
#pragma unroll
    for (int rq = 0; rq < 4; ++rq) {
      f32x4 o;
      o[0] = ot[dt][rq*4+0]*inv; o[1] = ot[dt][rq*4+1]*inv;
      o[2] = ot[dt][rq*4+2]*inv; o[3] = ot[dt][rq*4+3]*inv;
      *(f32x4*)(Ob + (size_t)qrow*DH + dt*32 + rq*8 + h2*4) = o;
    }
}

extern "C" void kernel_launch(void* const* d_in, const int* in_sizes, int n_in,
                              void* d_out, int out_size, void* d_ws, size_t ws_size,
                              hipStream_t stream)
{
  (void)in_sizes; (void)n_in; (void)out_size; (void)ws_size;
  const float* Q = (const float*)d_in[0];
  const float* K = (const float*)d_in[1];
  const float* V = (const float*)d_in[2];
  float* O = (float*)d_out;
  ushort_t* Kf = (ushort_t*)d_ws;                       // 16 MB
  ushort_t* Vf = Kf + (size_t)32*32*16*512;             // 16 MB

  hipLaunchKernelGGL(build_frags, dim3(1024), dim3(256), 0, stream, K, V, Kf, Vf);
  hipLaunchKernelGGL(sdpa_fwd,    dim3(256),  dim3(512), 0, stream, Q, Kf, Vf, O);
}